// Round 1
// baseline (488.668 us; speedup 1.0000x reference)
//
#include <hip/hip_runtime.h>

#define EPSB 1e-3f
#define BQ 64   // pixels per block along the q (dim-2) axis

// Shared inner loop: 3x3 conv over 16 input channels held in LDS.
// sIn layout: [dy(3)][qq(BQ+2)][ci(16)]
// sW  layout: [dxy(9)][ci(16)][co(64)]
// Each thread: 2 output channels (ch0, ch0+1) x 8 pixels (p0..p0+7).
__device__ __forceinline__ void conv_inner(const float* __restrict__ sIn,
                                           const float* __restrict__ sW,
                                           int p0, int ch0, float acc[8][2])
{
    #pragma unroll
    for (int dy = 0; dy < 3; ++dy) {
        const float* inrow = &sIn[dy * (BQ + 2) * 16];
        #pragma unroll
        for (int ci4 = 0; ci4 < 4; ++ci4) {
            float4 a[10];
            #pragma unroll
            for (int k = 0; k < 10; ++k)
                a[k] = *(const float4*)&inrow[(p0 + k) * 16 + ci4 * 4];
            #pragma unroll
            for (int dx = 0; dx < 3; ++dx) {
                const float* wp = &sW[((dy * 3 + dx) * 16 + ci4 * 4) * 64 + ch0];
                float2 w0 = *(const float2*)&wp[0];
                float2 w1 = *(const float2*)&wp[64];
                float2 w2 = *(const float2*)&wp[128];
                float2 w3 = *(const float2*)&wp[192];
                #pragma unroll
                for (int k = 0; k < 8; ++k) {
                    float4 av = a[k + dx];
                    acc[k][0] += av.x * w0.x + av.y * w1.x + av.z * w2.x + av.w * w3.x;
                    acc[k][1] += av.x * w0.y + av.y * w1.y + av.z * w2.y + av.w * w3.y;
                }
            }
        }
    }
}

// ---------------- Kernel 1: conv1 (16->64) + BN + ReLU ----------------
__global__ __launch_bounds__(256, 2)
void k_conv1(const float* __restrict__ in, const float* __restrict__ W1,
             const float* __restrict__ b1, const float* __restrict__ g1,
             const float* __restrict__ be1, const float* __restrict__ mu1,
             const float* __restrict__ v1, float* __restrict__ A)
{
    __shared__ float sW[9 * 16 * 64];
    __shared__ float sIn[3 * (BQ + 2) * 16];
    const int tid = threadIdx.x;
    const int bq = blockIdx.x & 3;
    const int r  = blockIdx.x >> 2;
    const int b  = blockIdx.y;
    const int q0 = bq * BQ;

    for (int idx = tid; idx < 9 * 16 * 64; idx += 256) sW[idx] = W1[idx];
    for (int idx = tid; idx < 3 * (BQ + 2) * 16; idx += 256) {
        int cil = idx & 15;
        int rem = idx >> 4;
        int qq  = rem % (BQ + 2);
        int dy  = rem / (BQ + 2);
        int rr = r + dy - 1, qg = q0 + qq - 1;
        float v = 0.f;
        if ((unsigned)rr < 256u && (unsigned)qg < 256u)
            v = in[((b * 256 + rr) * 256 + qg) * 16 + cil];
        sIn[idx] = v;
    }
    __syncthreads();

    const int m = tid & 31, pg = tid >> 5;
    const int ch0 = 2 * m, p0 = pg * 8;
    float acc[8][2];
    #pragma unroll
    for (int k = 0; k < 8; ++k) { acc[k][0] = 0.f; acc[k][1] = 0.f; }
    conv_inner(sIn, sW, p0, ch0, acc);

    float s0 = g1[ch0]     * rsqrtf(v1[ch0]     + EPSB);
    float s1 = g1[ch0 + 1] * rsqrtf(v1[ch0 + 1] + EPSB);
    float t0 = (b1[ch0]     - mu1[ch0])     * s0 + be1[ch0];
    float t1 = (b1[ch0 + 1] - mu1[ch0 + 1]) * s1 + be1[ch0 + 1];
    float* orow = &A[((b * 256 + r) * 256 + q0 + p0) * 64 + ch0];
    #pragma unroll
    for (int k = 0; k < 8; ++k) {
        float y0 = fmaxf(acc[k][0] * s0 + t0, 0.f);
        float y1 = fmaxf(acc[k][1] * s1 + t1, 0.f);
        *(float2*)&orow[k * 64] = make_float2(y0, y1);
    }
}

// ---------- Kernel 2: conv2 (64->64) + BN + softmax(groups of 4) + mask ----------
__global__ __launch_bounds__(256, 2)
void k_conv2(const float* __restrict__ A, const float* __restrict__ W2,
             const float* __restrict__ b2, const float* __restrict__ g2,
             const float* __restrict__ be2, const float* __restrict__ mu2,
             const float* __restrict__ v2, float* __restrict__ BF)
{
    __shared__ float sW[9 * 16 * 64];
    __shared__ float sIn[3 * (BQ + 2) * 16];
    const int tid = threadIdx.x;
    const int bq = blockIdx.x & 3;
    const int r  = blockIdx.x >> 2;
    const int b  = blockIdx.y;
    const int q0 = bq * BQ;
    const int m = tid & 31, pg = tid >> 5;
    const int ch0 = 2 * m, p0 = pg * 8;

    float acc[8][2];
    #pragma unroll
    for (int k = 0; k < 8; ++k) { acc[k][0] = 0.f; acc[k][1] = 0.f; }

    for (int cc = 0; cc < 4; ++cc) {   // 4 chunks of 16 input channels
        __syncthreads();
        for (int idx = tid; idx < 3 * (BQ + 2) * 16; idx += 256) {
            int cil = idx & 15;
            int rem = idx >> 4;
            int qq  = rem % (BQ + 2);
            int dy  = rem / (BQ + 2);
            int rr = r + dy - 1, qg = q0 + qq - 1;
            float v = 0.f;
            if ((unsigned)rr < 256u && (unsigned)qg < 256u)
                v = A[((b * 256 + rr) * 256 + qg) * 64 + cc * 16 + cil];
            sIn[idx] = v;
        }
        for (int idx = tid; idx < 9216; idx += 256) {
            int ch   = idx & 63;
            int rest = idx >> 6;           // dxy*16 + cil
            int dxy  = rest >> 4, cil = rest & 15;
            sW[idx] = W2[(dxy * 64 + cc * 16 + cil) * 64 + ch];
        }
        __syncthreads();
        conv_inner(sIn, sW, p0, ch0, acc);
    }

    float s0 = g2[ch0]     * rsqrtf(v2[ch0]     + EPSB);
    float s1 = g2[ch0 + 1] * rsqrtf(v2[ch0 + 1] + EPSB);
    float t0 = (b2[ch0]     - mu2[ch0])     * s0 + be2[ch0];
    float t1 = (b2[ch0 + 1] - mu2[ch0 + 1]) * s1 + be2[ch0 + 1];
    float* orow = &BF[((b * 256 + r) * 256 + q0 + p0) * 64 + ch0];
    #pragma unroll
    for (int k = 0; k < 8; ++k) {
        float z0 = acc[k][0] * s0 + t0;
        float z1 = acc[k][1] * s1 + t1;
        // softmax group = 4 consecutive channels = this lane (2) + lane^1 (2)
        float oz0 = __shfl_xor(z0, 1);
        float oz1 = __shfl_xor(z1, 1);
        float mx = fmaxf(fmaxf(z0, z1), fmaxf(oz0, oz1));
        float e0 = expf(z0 - mx), e1 = expf(z1 - mx);
        float es = e0 + e1;
        float inv = 1.f / (es + __shfl_xor(es, 1));
        float p0v = e0 * inv, p1v = e1 * inv;
        p0v = (p0v > 1e-5f) ? p0v : 0.f;
        p1v = (p1v > 1e-5f) ? p1v : 0.f;
        *(float2*)&orow[k * 64] = make_float2(p0v, p1v);
    }
}

// ---------- Kernel 3: per-patch dn / kp -> ratio[b, i, j, c, f] ----------
__global__ __launch_bounds__(256, 4)
void k_ratio(const float* __restrict__ BF, const float* __restrict__ pet,
             float* __restrict__ RATIO)
{
    const int tid = threadIdx.x;
    const int cf = tid & 63, jl = tid >> 6;
    const int i  = blockIdx.x >> 4;
    const int jt = blockIdx.x & 15;
    const int b  = blockIdx.y;
    const int j  = jt * 4 + jl;
    const int c  = cf >> 2;
    float dn = 0.f, kp = 0.f;
    #pragma unroll
    for (int u = 0; u < 8; ++u) {
        int rr = i * 4 + u - 2;
        if ((unsigned)rr >= 256u) continue;
        #pragma unroll
        for (int v = 0; v < 8; ++v) {
            int qq = j * 4 + v - 2;
            if ((unsigned)qq >= 256u) continue;
            float bv = BF[((b * 256 + rr) * 256 + qq) * 64 + cf];
            float pv = pet[((b * 256 + rr) * 256 + qq) * 16 + c];
            dn += bv;
            kp = fmaf(pv, bv, kp);
        }
    }
    RATIO[((b * 64 + i) * 64 + j) * 64 + cf] = (dn == 0.f) ? 0.f : kp / dn;
}

// ---------- Kernel 4: out[b,x,y,c] = 0.25 * sum_f bf * sum_phases ratio ----------
__global__ __launch_bounds__(256, 4)
void k_out(const float* __restrict__ BF, const float* __restrict__ RATIO,
           float* __restrict__ out)
{
    int tid = blockIdx.x * 256 + threadIdx.x;
    int c = tid & 15;
    int q = (tid >> 4) & 255;
    int r = (tid >> 12) & 255;
    int b = tid >> 20;
    // phase patch indices (derived: patch row == output row when valid)
    int i0 = (r <= 253) ? (((r + 2) >> 3) << 1)       : -1;
    int i1 = (r >= 2)   ? (((((r - 2) >> 3) << 1)) | 1) : -1;
    int j0 = (q <= 253) ? (((q + 2) >> 3) << 1)       : -1;
    int j1 = (q >= 2)   ? (((((q - 2) >> 3) << 1)) | 1) : -1;
    float Sx = 0.f, Sy = 0.f, Sz = 0.f, Sw = 0.f;
    const float* Rb = &RATIO[(size_t)b * 64 * 64 * 64 + 4 * c];
    #pragma unroll
    for (int pi = 0; pi < 2; ++pi) {
        int ii = pi ? i1 : i0;
        if (ii < 0) continue;
        #pragma unroll
        for (int pj = 0; pj < 2; ++pj) {
            int jj = pj ? j1 : j0;
            if (jj < 0) continue;
            float4 r4 = *(const float4*)&Rb[(ii * 64 + jj) * 64];
            Sx += r4.x; Sy += r4.y; Sz += r4.z; Sw += r4.w;
        }
    }
    float4 bf4 = *(const float4*)&BF[(size_t)tid * 4];
    out[tid] = 0.25f * (bf4.x * Sx + bf4.y * Sy + bf4.z * Sz + bf4.w * Sw);
}

extern "C" void kernel_launch(void* const* d_in, const int* in_sizes, int n_in,
                              void* d_out, int out_size, void* d_ws, size_t ws_size,
                              hipStream_t stream) {
    const float* mr  = (const float*)d_in[0];
    const float* pet = (const float*)d_in[1];
    const float* W1  = (const float*)d_in[2];
    const float* b1  = (const float*)d_in[3];
    const float* g1  = (const float*)d_in[4];
    const float* be1 = (const float*)d_in[5];
    const float* mu1 = (const float*)d_in[6];
    const float* v1  = (const float*)d_in[7];
    const float* W2  = (const float*)d_in[8];
    const float* b2  = (const float*)d_in[9];
    const float* g2  = (const float*)d_in[10];
    const float* be2 = (const float*)d_in[11];
    const float* mu2 = (const float*)d_in[12];
    const float* v2  = (const float*)d_in[13];
    // d_in[14]=patch(8), d_in[15]=stride(4) — fixed by problem shape

    float* ws    = (float*)d_ws;
    float* A     = ws;                 // 3*256*256*64 = 12,582,912 floats
    float* BF    = ws + 12582912;      // 3*256*256*64
    float* RATIO = ws;                 // reuse A's region after conv2 (786,432 floats)
    float* out   = (float*)d_out;

    dim3 blk(256);
    k_conv1<<<dim3(1024, 3), blk, 0, stream>>>(mr, W1, b1, g1, be1, mu1, v1, A);
    k_conv2<<<dim3(1024, 3), blk, 0, stream>>>(A, W2, b2, g2, be2, mu2, v2, BF);
    k_ratio<<<dim3(1024, 3), blk, 0, stream>>>(BF, pet, RATIO);
    k_out<<<12288, blk, 0, stream>>>(BF, RATIO, out);
}

// Round 2
// 200.408 us; speedup vs baseline: 2.4384x; 2.4384x over previous
//
#include <hip/hip_runtime.h>

#define EPSB 1e-3f

typedef _Float16 half8 __attribute__((ext_vector_type(8)));
typedef _Float16 half4 __attribute__((ext_vector_type(4)));
typedef float f32x4 __attribute__((ext_vector_type(4)));

// ---------------- prep: weight transpose->f16, mr->f16, BN fold ----------------
__global__ __launch_bounds__(256, 4)
void k_prep(const float* __restrict__ mr, const float* __restrict__ W1,
            const float* __restrict__ W2,
            const float* __restrict__ b1, const float* __restrict__ g1,
            const float* __restrict__ be1, const float* __restrict__ mu1,
            const float* __restrict__ v1,
            const float* __restrict__ b2, const float* __restrict__ g2,
            const float* __restrict__ be2, const float* __restrict__ mu2,
            const float* __restrict__ v2,
            _Float16* __restrict__ Xf, _Float16* __restrict__ W1T,
            _Float16* __restrict__ W2T, float* __restrict__ ST)
{
    int t = blockIdx.x * 256 + threadIdx.x;
    const int NMR4 = 3 * 256 * 256 * 16 / 4;      // 786432
    if (t < NMR4) {
        float4 v = *(const float4*)(mr + 4 * t);
        half4 h = { (_Float16)v.x, (_Float16)v.y, (_Float16)v.z, (_Float16)v.w };
        *(half4*)(Xf + 4 * t) = h;
        return;
    }
    t -= NMR4;
    if (t < 10 * 64 * 16) {                       // W1T[(tap*64+co)*16+ci], tap 9 = zero pad
        int ci = t & 15, co = (t >> 4) & 63, tap = t >> 10;
        float v = (tap < 9) ? W1[(tap * 16 + ci) * 64 + co] : 0.f;
        W1T[t] = (_Float16)v;
        return;
    }
    t -= 10 * 64 * 16;
    if (t < 9 * 64 * 64) {                        // W2T[(tap*64+co)*64+ci]
        int ci = t & 63, co = (t >> 6) & 63, tap = t >> 12;
        W2T[t] = (_Float16)W2[(tap * 64 + ci) * 64 + co];
        return;
    }
    t -= 9 * 64 * 64;
    if (t < 256) {
        int c = t & 63, sel = t >> 6;
        if (sel == 0)      ST[c]       = g1[c] * rsqrtf(v1[c] + EPSB);
        else if (sel == 1) ST[64 + c]  = (b1[c] - mu1[c]) * (g1[c] * rsqrtf(v1[c] + EPSB)) + be1[c];
        else if (sel == 2) ST[128 + c] = g2[c] * rsqrtf(v2[c] + EPSB);
        else               ST[192 + c] = (b2[c] - mu2[c]) * (g2[c] * rsqrtf(v2[c] + EPSB)) + be2[c];
    }
}

// ---------------- conv1: 16->64, MFMA, BN+ReLU, f16 out ----------------
#define CIP1 24   // padded ci stride (f16): 48B = 4*3 dwords -> aligned b128, <=2-way banks
__global__ __launch_bounds__(256, 1)
void k_conv1(const _Float16* __restrict__ X, const _Float16* __restrict__ W1T,
             const float* __restrict__ ST, _Float16* __restrict__ A)
{
    __shared__ __align__(16) _Float16 sIn[6 * 66 * CIP1];
    __shared__ __align__(16) _Float16 sW[10 * 64 * CIP1];
    const int tid = threadIdx.x;
    const int b  = blockIdx.y;
    const int r0 = (blockIdx.x >> 2) * 4;
    const int q0 = (blockIdx.x & 3) * 64;

    for (int idx = tid; idx < 6 * 66 * 2; idx += 256) {
        int c = idx & 1, pp = idx >> 1;
        int p = pp % 66, dy = pp / 66;
        int rr = r0 + dy - 1, qg = q0 + p - 1;
        int4 v = {0, 0, 0, 0};
        if ((unsigned)rr < 256u && (unsigned)qg < 256u)
            v = *(const int4*)(X + (((b * 256 + rr) * 256 + qg) * 16 + c * 8));
        *(int4*)(&sIn[(dy * 66 + p) * CIP1 + c * 8]) = v;
    }
    for (int idx = tid; idx < 10 * 64 * 2; idx += 256) {
        int c = idx & 1, row = idx >> 1;
        int4 v = *(const int4*)(W1T + row * 16 + c * 8);
        *(int4*)(&sW[row * CIP1 + c * 8]) = v;
    }
    __syncthreads();

    const int w = tid >> 6, lane = tid & 63;
    const int n16 = lane & 15, quad = lane >> 4;

    f32x4 acc[4][4];
    #pragma unroll
    for (int i = 0; i < 4; ++i)
        #pragma unroll
        for (int j = 0; j < 4; ++j) acc[i][j] = (f32x4){0.f, 0.f, 0.f, 0.f};

    #pragma unroll
    for (int s = 0; s < 5; ++s) {
        int tap  = 2 * s + (quad >> 1);      // lane-dependent
        int tapc = tap > 8 ? 8 : tap;        // tap 9 = zero-weight pad; clamp input addr
        int dy = tapc / 3, dx = tapc % 3;
        int ci0 = (quad & 1) * 8;
        half8 bfrag[4], afrag[4];
        #pragma unroll
        for (int nt = 0; nt < 4; ++nt)
            bfrag[nt] = *(const half8*)&sW[(tap * 64 + nt * 16 + n16) * CIP1 + ci0];
        #pragma unroll
        for (int mt = 0; mt < 4; ++mt)
            afrag[mt] = *(const half8*)&sIn[((w + dy) * 66 + mt * 16 + n16 + dx) * CIP1 + ci0];
        #pragma unroll
        for (int mt = 0; mt < 4; ++mt)
            #pragma unroll
            for (int nt = 0; nt < 4; ++nt)
                acc[mt][nt] = __builtin_amdgcn_mfma_f32_16x16x32_f16(afrag[mt], bfrag[nt], acc[mt][nt], 0, 0, 0);
    }

    const int r = r0 + w;
    #pragma unroll
    for (int nt = 0; nt < 4; ++nt) {
        int co = nt * 16 + n16;
        float sc = ST[co], sh = ST[64 + co];
        #pragma unroll
        for (int mt = 0; mt < 4; ++mt)
            #pragma unroll
            for (int j = 0; j < 4; ++j) {
                int q = q0 + mt * 16 + quad * 4 + j;
                float y = fmaxf(acc[mt][nt][j] * sc + sh, 0.f);
                A[((b * 256 + r) * 256 + q) * 64 + co] = (_Float16)y;
            }
    }
}

// ---------------- conv2: 64->64, MFMA, BN + softmax(4) + mask, fp32 out ----------------
#define CIP2 72   // 144B = 4*9 dwords -> aligned b128, <=2-way banks
__global__ __launch_bounds__(256, 1)
void k_conv2(const _Float16* __restrict__ A, const _Float16* __restrict__ W2T,
             const float* __restrict__ ST, float* __restrict__ BF)
{
    __shared__ __align__(16) _Float16 sIn[6 * 66 * CIP2];   // 57,024 B
    __shared__ __align__(16) _Float16 sW[9 * 64 * CIP2];    // 82,944 B
    const int tid = threadIdx.x;
    const int b  = blockIdx.y;
    const int r0 = (blockIdx.x >> 2) * 4;
    const int q0 = (blockIdx.x & 3) * 64;

    for (int idx = tid; idx < 6 * 66 * 8; idx += 256) {
        int c = idx & 7, pp = idx >> 3;
        int p = pp % 66, dy = pp / 66;
        int rr = r0 + dy - 1, qg = q0 + p - 1;
        int4 v = {0, 0, 0, 0};
        if ((unsigned)rr < 256u && (unsigned)qg < 256u)
            v = *(const int4*)(A + (((b * 256 + rr) * 256 + qg) * 64 + c * 8));
        *(int4*)(&sIn[(dy * 66 + p) * CIP2 + c * 8]) = v;
    }
    for (int idx = tid; idx < 9 * 64 * 8; idx += 256) {
        int c = idx & 7, row = idx >> 3;
        int4 v = *(const int4*)(W2T + row * 64 + c * 8);
        *(int4*)(&sW[row * CIP2 + c * 8]) = v;
    }
    __syncthreads();

    const int w = tid >> 6, lane = tid & 63;
    const int n16 = lane & 15, quad = lane >> 4;

    f32x4 acc[4][4];
    #pragma unroll
    for (int i = 0; i < 4; ++i)
        #pragma unroll
        for (int j = 0; j < 4; ++j) acc[i][j] = (f32x4){0.f, 0.f, 0.f, 0.f};

    #pragma unroll
    for (int s = 0; s < 18; ++s) {
        const int tap = s >> 1;
        const int dy = tap / 3, dx = tap % 3;
        const int ci0 = (s & 1) * 32 + quad * 8;
        half8 bfrag[4], afrag[4];
        #pragma unroll
        for (int nt = 0; nt < 4; ++nt)
            bfrag[nt] = *(const half8*)&sW[(tap * 64 + nt * 16 + n16) * CIP2 + ci0];
        #pragma unroll
        for (int mt = 0; mt < 4; ++mt)
            afrag[mt] = *(const half8*)&sIn[((w + dy) * 66 + mt * 16 + n16 + dx) * CIP2 + ci0];
        #pragma unroll
        for (int mt = 0; mt < 4; ++mt)
            #pragma unroll
            for (int nt = 0; nt < 4; ++nt)
                acc[mt][nt] = __builtin_amdgcn_mfma_f32_16x16x32_f16(afrag[mt], bfrag[nt], acc[mt][nt], 0, 0, 0);
    }

    const int r = r0 + w;
    #pragma unroll
    for (int nt = 0; nt < 4; ++nt) {
        int co = nt * 16 + n16;
        float sc = ST[128 + co], sh = ST[192 + co];
        #pragma unroll
        for (int mt = 0; mt < 4; ++mt)
            #pragma unroll
            for (int j = 0; j < 4; ++j) {
                float z = acc[mt][nt][j] * sc + sh;
                // softmax over 4 consecutive channels = 4 adjacent lanes (xor 1,2 -> DPP)
                float e  = __expf(z);
                float e2 = e + __shfl_xor(e, 1);
                float s4 = e2 + __shfl_xor(e2, 2);
                float p = e / s4;
                p = (p > 1e-5f) ? p : 0.f;
                int q = q0 + mt * 16 + quad * 4 + j;
                BF[((b * 256 + r) * 256 + q) * 64 + co] = p;
            }
    }
}

// ---------------- s2: 2x2 cell sums of (dn, pet*dn) ----------------
__global__ __launch_bounds__(256, 4)
void k_s2(const float* __restrict__ BF, const float* __restrict__ pet,
          float* __restrict__ S2)
{
    int t = blockIdx.x * 256 + threadIdx.x;
    int cf = t & 63;
    int q2 = (t >> 6) & 127;
    int r2 = (t >> 13) & 127;
    int b  = t >> 20;
    int c  = cf >> 2;
    float dn = 0.f, kp = 0.f;
    #pragma unroll
    for (int u = 0; u < 2; ++u)
        #pragma unroll
        for (int v = 0; v < 2; ++v) {
            int rr = 2 * r2 + u, qq = 2 * q2 + v;
            float bv = BF[((b * 256 + rr) * 256 + qq) * 64 + cf];
            float pv = pet[((b * 256 + rr) * 256 + qq) * 16 + c];
            dn += bv;
            kp = fmaf(pv, bv, kp);
        }
    *(float2*)(S2 + 2 * t) = make_float2(dn, kp);
}

// ---------------- ratio: 4x4 cells -> kp/dn per patch ----------------
__global__ __launch_bounds__(256, 4)
void k_ratio(const float* __restrict__ S2, float* __restrict__ RATIO)
{
    int t = blockIdx.x * 256 + threadIdx.x;
    int cf = t & 63;
    int j  = (t >> 6) & 63;
    int i  = (t >> 12) & 63;
    int b  = t >> 18;
    float dn = 0.f, kp = 0.f;
    #pragma unroll
    for (int u = 0; u < 4; ++u) {
        int r2 = 2 * i - 1 + u;
        if ((unsigned)r2 >= 128u) continue;
        #pragma unroll
        for (int v = 0; v < 4; ++v) {
            int q2 = 2 * j - 1 + v;
            if ((unsigned)q2 >= 128u) continue;
            float2 s = *(const float2*)(S2 + 2 * (((b * 128 + r2) * 128 + q2) * 64 + cf));
            dn += s.x;
            kp += s.y;
        }
    }
    RATIO[t] = (dn == 0.f) ? 0.f : kp / dn;
}

// ---------------- out: gather 4 phase ratios, dot with bf ----------------
__global__ __launch_bounds__(256, 4)
void k_out(const float* __restrict__ BF, const float* __restrict__ RATIO,
           float* __restrict__ out)
{
    int tid = blockIdx.x * 256 + threadIdx.x;
    int c = tid & 15;
    int q = (tid >> 4) & 255;
    int r = (tid >> 12) & 255;
    int b = tid >> 20;
    int i0 = (r <= 253) ? (((r + 2) >> 3) << 1)        : -1;
    int i1 = (r >= 2)   ? ((((r - 2) >> 3) << 1) | 1)  : -1;
    int j0 = (q <= 253) ? (((q + 2) >> 3) << 1)        : -1;
    int j1 = (q >= 2)   ? ((((q - 2) >> 3) << 1) | 1)  : -1;
    float Sx = 0.f, Sy = 0.f, Sz = 0.f, Sw = 0.f;
    const float* Rb = &RATIO[(size_t)b * 64 * 64 * 64 + 4 * c];
    #pragma unroll
    for (int pi = 0; pi < 2; ++pi) {
        int ii = pi ? i1 : i0;
        if (ii < 0) continue;
        #pragma unroll
        for (int pj = 0; pj < 2; ++pj) {
            int jj = pj ? j1 : j0;
            if (jj < 0) continue;
            float4 r4 = *(const float4*)&Rb[(ii * 64 + jj) * 64];
            Sx += r4.x; Sy += r4.y; Sz += r4.z; Sw += r4.w;
        }
    }
    float4 bf4 = *(const float4*)&BF[(size_t)tid * 4];
    out[tid] = 0.25f * (bf4.x * Sx + bf4.y * Sy + bf4.z * Sz + bf4.w * Sw);
}

extern "C" void kernel_launch(void* const* d_in, const int* in_sizes, int n_in,
                              void* d_out, int out_size, void* d_ws, size_t ws_size,
                              hipStream_t stream) {
    const float* mr  = (const float*)d_in[0];
    const float* pet = (const float*)d_in[1];
    const float* W1  = (const float*)d_in[2];
    const float* b1  = (const float*)d_in[3];
    const float* g1  = (const float*)d_in[4];
    const float* be1 = (const float*)d_in[5];
    const float* mu1 = (const float*)d_in[6];
    const float* v1  = (const float*)d_in[7];
    const float* W2  = (const float*)d_in[8];
    const float* b2  = (const float*)d_in[9];
    const float* g2  = (const float*)d_in[10];
    const float* be2 = (const float*)d_in[11];
    const float* mu2 = (const float*)d_in[12];
    const float* v2  = (const float*)d_in[13];

    // workspace layout (bytes):
    //   [0,        25165824)  A_f16 (3*256*256*64 f16)  -> reused as S2 (float2) after conv2
    //   [25165824, 75497472)  BF (fp32)
    //   [75497472, 81788928)  Xf (mr f16)               -> reused as RATIO (fp32) after conv1
    //   [81788928, 81809408)  W1T f16
    //   [81809408, 81883136)  W2T f16
    //   [81883136, 81884160)  ST (4*64 fp32)
    char* ws = (char*)d_ws;
    _Float16* A_f16 = (_Float16*)(ws);
    float*    BF    = (float*)(ws + 25165824);
    _Float16* Xf    = (_Float16*)(ws + 75497472);
    _Float16* W1T   = (_Float16*)(ws + 81788928);
    _Float16* W2T   = (_Float16*)(ws + 81809408);
    float*    ST    = (float*)(ws + 81883136);
    float*    S2    = (float*)(ws);               // aliases A_f16 (dead after conv2)
    float*    RATIO = (float*)(ws + 75497472);    // aliases Xf (dead after conv1)
    float*    out   = (float*)d_out;

    dim3 blk(256);
    k_prep<<<3257, blk, 0, stream>>>(mr, W1, W2, b1, g1, be1, mu1, v1,
                                     b2, g2, be2, mu2, v2, Xf, W1T, W2T, ST);
    k_conv1<<<dim3(256, 3), blk, 0, stream>>>(Xf, W1T, ST, A_f16);
    k_conv2<<<dim3(256, 3), blk, 0, stream>>>(A_f16, W2T, ST, BF);
    k_s2<<<12288, blk, 0, stream>>>(BF, pet, S2);
    k_ratio<<<3072, blk, 0, stream>>>(S2, RATIO);
    k_out<<<12288, blk, 0, stream>>>(BF, RATIO, out);
}

// Round 3
// 177.662 us; speedup vs baseline: 2.7505x; 1.1280x over previous
//
#include <hip/hip_runtime.h>

#define EPSB 1e-3f

typedef _Float16 half8 __attribute__((ext_vector_type(8)));
typedef _Float16 half4 __attribute__((ext_vector_type(4)));
typedef float f32x4 __attribute__((ext_vector_type(4)));

// ---------------- prep: weights -> MFMA-fragment order (f16), BN fold ----------------
// WF layout: frag (s, ct) is 1 KB: WF[((s*4+ct)*64 + lane)*8 + k]
// A-operand mapping (16x16x32): m = lane&15 -> co = ct*16 + (lane&15)
//                               k = (lane>>4)*8 + j -> K index
// conv2: K = (tap = s>>1, ci = (s&1)*32 + quad*8 + j)
// conv1: K = (tap = 2s + (quad>>1), ci = (quad&1)*8 + j), tap==9 -> 0
__global__ __launch_bounds__(256, 4)
void k_prep(const float* __restrict__ W1, const float* __restrict__ W2,
            const float* __restrict__ b1, const float* __restrict__ g1,
            const float* __restrict__ be1, const float* __restrict__ mu1,
            const float* __restrict__ v1,
            const float* __restrict__ b2, const float* __restrict__ g2,
            const float* __restrict__ be2, const float* __restrict__ mu2,
            const float* __restrict__ v2,
            _Float16* __restrict__ W1F, _Float16* __restrict__ W2F,
            float* __restrict__ ST)
{
    int t = blockIdx.x * 256 + threadIdx.x;
    if (t < 5 * 4 * 64 * 8) {                 // W1F
        int k = t & 7, lane = (t >> 3) & 63, snt = t >> 9;
        int s = snt >> 2, ct = snt & 3;
        int quad = lane >> 4, n16 = lane & 15;
        int tap = 2 * s + (quad >> 1);
        int ci  = (quad & 1) * 8 + k;
        int co  = ct * 16 + n16;
        float v = (tap < 9) ? W1[(tap * 16 + ci) * 64 + co] : 0.f;
        W1F[t] = (_Float16)v;
        return;
    }
    t -= 5 * 4 * 64 * 8;
    if (t < 18 * 4 * 64 * 8) {                // W2F
        int k = t & 7, lane = (t >> 3) & 63, snt = t >> 9;
        int s = snt >> 2, ct = snt & 3;
        int quad = lane >> 4, n16 = lane & 15;
        int tap = s >> 1;
        int ci  = (s & 1) * 32 + quad * 8 + k;
        int co  = ct * 16 + n16;
        W2F[t] = (_Float16)W2[(tap * 64 + ci) * 64 + co];
        return;
    }
    t -= 18 * 4 * 64 * 8;
    if (t < 256) {
        int c = t & 63, sel = t >> 6;
        if (sel == 0)      ST[c]       = g1[c] * rsqrtf(v1[c] + EPSB);
        else if (sel == 1) ST[64 + c]  = (b1[c] - mu1[c]) * (g1[c] * rsqrtf(v1[c] + EPSB)) + be1[c];
        else if (sel == 2) ST[128 + c] = g2[c] * rsqrtf(v2[c] + EPSB);
        else               ST[192 + c] = (b2[c] - mu2[c]) * (g2[c] * rsqrtf(v2[c] + EPSB)) + be2[c];
    }
}

// ---------------- conv1: 16->64, MFMA (weights=A from global), BN+ReLU, f16 out ----------------
#define CIP1 24   // padded pixel stride in f16 (48 B)
__global__ __launch_bounds__(256, 2)
void k_conv1(const float* __restrict__ mr, const _Float16* __restrict__ W1F,
             const float* __restrict__ ST, _Float16* __restrict__ A)
{
    __shared__ __align__(16) _Float16 sIn[6 * 66 * CIP1];
    const int tid = threadIdx.x;
    const int b  = blockIdx.y;
    const int r0 = (blockIdx.x >> 2) * 4;
    const int q0 = (blockIdx.x & 3) * 64;

    for (int idx = tid; idx < 6 * 66 * 2; idx += 256) {
        int c = idx & 1, pp = idx >> 1;
        int p = pp % 66, dy = pp / 66;
        int rr = r0 + dy - 1, qg = q0 + p - 1;
        half8 h = (half8)(_Float16)0.f;
        if ((unsigned)rr < 256u && (unsigned)qg < 256u) {
            const float* src = mr + ((b * 256 + rr) * 256 + qg) * 16 + c * 8;
            float4 v0 = *(const float4*)src;
            float4 v1 = *(const float4*)(src + 4);
            h = (half8){(_Float16)v0.x, (_Float16)v0.y, (_Float16)v0.z, (_Float16)v0.w,
                        (_Float16)v1.x, (_Float16)v1.y, (_Float16)v1.z, (_Float16)v1.w};
        }
        *(half8*)(&sIn[(dy * 66 + p) * CIP1 + c * 8]) = h;
    }
    __syncthreads();

    const int w = tid >> 6, lane = tid & 63;
    const int n16 = lane & 15, quad = lane >> 4;
    const int ci0 = (quad & 1) * 8;

    f32x4 acc[4][4];   // [qt][ct]
    #pragma unroll
    for (int i = 0; i < 4; ++i)
        #pragma unroll
        for (int j = 0; j < 4; ++j) acc[i][j] = (f32x4){0.f, 0.f, 0.f, 0.f};

    #pragma unroll
    for (int s = 0; s < 5; ++s) {
        int tap  = 2 * s + (quad >> 1);
        int tapc = tap > 8 ? 8 : tap;
        int dy = tapc / 3, dx = tapc % 3;
        half8 wfrag[4], pfrag[4];
        #pragma unroll
        for (int ct = 0; ct < 4; ++ct)
            wfrag[ct] = *(const half8*)(W1F + ((s * 4 + ct) * 64 + lane) * 8);
        #pragma unroll
        for (int qt = 0; qt < 4; ++qt)
            pfrag[qt] = *(const half8*)&sIn[((w + dy) * 66 + qt * 16 + n16 + dx) * CIP1 + ci0];
        #pragma unroll
        for (int qt = 0; qt < 4; ++qt)
            #pragma unroll
            for (int ct = 0; ct < 4; ++ct)
                acc[qt][ct] = __builtin_amdgcn_mfma_f32_16x16x32_f16(wfrag[ct], pfrag[qt], acc[qt][ct], 0, 0, 0);
    }

    const int r = r0 + w;
    #pragma unroll
    for (int ct = 0; ct < 4; ++ct) {
        int co0 = ct * 16 + quad * 4;
        f32x4 sc = *(const f32x4*)&ST[co0];
        f32x4 sh = *(const f32x4*)&ST[64 + co0];
        #pragma unroll
        for (int qt = 0; qt < 4; ++qt) {
            int q = q0 + qt * 16 + n16;
            half4 h;
            #pragma unroll
            for (int j = 0; j < 4; ++j)
                h[j] = (_Float16)fmaxf(acc[qt][ct][j] * sc[j] + sh[j], 0.f);
            *(half4*)(A + (((b * 256 + r) * 256 + q) * 64 + co0)) = h;
        }
    }
}

// ---------------- conv2: 64->64, MFMA, BN + in-lane softmax(4) + mask, f16 out ----------------
#define CIP2 72   // padded pixel stride in f16 (144 B)
__global__ __launch_bounds__(256, 2)
void k_conv2(const _Float16* __restrict__ A, const _Float16* __restrict__ W2F,
             const float* __restrict__ ST, _Float16* __restrict__ BF)
{
    __shared__ __align__(16) _Float16 sIn[6 * 66 * CIP2];   // 57,024 B
    const int tid = threadIdx.x;
    const int b  = blockIdx.y;
    const int r0 = (blockIdx.x >> 2) * 4;
    const int q0 = (blockIdx.x & 3) * 64;

    for (int idx = tid; idx < 6 * 66 * 8; idx += 256) {
        int c = idx & 7, pp = idx >> 3;
        int p = pp % 66, dy = pp / 66;
        int rr = r0 + dy - 1, qg = q0 + p - 1;
        int4 v = {0, 0, 0, 0};
        if ((unsigned)rr < 256u && (unsigned)qg < 256u)
            v = *(const int4*)(A + (((b * 256 + rr) * 256 + qg) * 64 + c * 8));
        *(int4*)(&sIn[(dy * 66 + p) * CIP2 + c * 8]) = v;
    }
    __syncthreads();

    const int w = tid >> 6, lane = tid & 63;
    const int n16 = lane & 15, quad = lane >> 4;

    f32x4 acc[4][4];   // [qt][ct]
    #pragma unroll
    for (int i = 0; i < 4; ++i)
        #pragma unroll
        for (int j = 0; j < 4; ++j) acc[i][j] = (f32x4){0.f, 0.f, 0.f, 0.f};

    #pragma unroll
    for (int s = 0; s < 18; ++s) {
        const int tap = s >> 1;
        const int dy = tap / 3, dx = tap % 3;
        const int ci0 = (s & 1) * 32 + quad * 8;
        half8 wfrag[4], pfrag[4];
        #pragma unroll
        for (int ct = 0; ct < 4; ++ct)
            wfrag[ct] = *(const half8*)(W2F + ((s * 4 + ct) * 64 + lane) * 8);
        #pragma unroll
        for (int qt = 0; qt < 4; ++qt)
            pfrag[qt] = *(const half8*)&sIn[((w + dy) * 66 + qt * 16 + n16 + dx) * CIP2 + ci0];
        #pragma unroll
        for (int qt = 0; qt < 4; ++qt)
            #pragma unroll
            for (int ct = 0; ct < 4; ++ct)
                acc[qt][ct] = __builtin_amdgcn_mfma_f32_16x16x32_f16(wfrag[ct], pfrag[qt], acc[qt][ct], 0, 0, 0);
    }

    const int r = r0 + w;
    #pragma unroll
    for (int ct = 0; ct < 4; ++ct) {
        int co0 = ct * 16 + quad * 4;     // softmax group = co0..co0+3, all in-lane
        f32x4 sc = *(const f32x4*)&ST[128 + co0];
        f32x4 sh = *(const f32x4*)&ST[192 + co0];
        #pragma unroll
        for (int qt = 0; qt < 4; ++qt) {
            int q = q0 + qt * 16 + n16;
            float z0 = acc[qt][ct][0] * sc[0] + sh[0];
            float z1 = acc[qt][ct][1] * sc[1] + sh[1];
            float z2 = acc[qt][ct][2] * sc[2] + sh[2];
            float z3 = acc[qt][ct][3] * sc[3] + sh[3];
            float mx = fmaxf(fmaxf(z0, z1), fmaxf(z2, z3));
            float e0 = __expf(z0 - mx), e1 = __expf(z1 - mx);
            float e2 = __expf(z2 - mx), e3 = __expf(z3 - mx);
            float inv = __builtin_amdgcn_rcpf((e0 + e1) + (e2 + e3));
            float p0 = e0 * inv, p1 = e1 * inv, p2 = e2 * inv, p3 = e3 * inv;
            half4 h;
            h[0] = (_Float16)(p0 > 1e-5f ? p0 : 0.f);
            h[1] = (_Float16)(p1 > 1e-5f ? p1 : 0.f);
            h[2] = (_Float16)(p2 > 1e-5f ? p2 : 0.f);
            h[3] = (_Float16)(p3 > 1e-5f ? p3 : 0.f);
            *(half4*)(BF + (((b * 256 + r) * 256 + q) * 64 + co0)) = h;
        }
    }
}

// ---------------- s2: 2x2 cell sums of (dn, pet*dn), BF f16 ----------------
__global__ __launch_bounds__(256, 4)
void k_s2(const _Float16* __restrict__ BF, const float* __restrict__ pet,
          float* __restrict__ S2)
{
    int t = blockIdx.x * 256 + threadIdx.x;
    int c8 = t & 7;
    int q2 = (t >> 3) & 127;
    int r2 = (t >> 10) & 127;
    int b  = t >> 17;
    float dn[8], kp[8];
    #pragma unroll
    for (int k = 0; k < 8; ++k) { dn[k] = 0.f; kp[k] = 0.f; }
    #pragma unroll
    for (int u = 0; u < 2; ++u)
        #pragma unroll
        for (int v = 0; v < 2; ++v) {
            int rr = 2 * r2 + u, qq = 2 * q2 + v;
            half8 bf = *(const half8*)(BF + (((b * 256 + rr) * 256 + qq) * 64 + c8 * 8));
            float2 pv = *(const float2*)(pet + ((b * 256 + rr) * 256 + qq) * 16 + c8 * 2);
            #pragma unroll
            for (int k = 0; k < 8; ++k) {
                float bv = (float)bf[k];
                dn[k] += bv;
                kp[k] = fmaf(k < 4 ? pv.x : pv.y, bv, kp[k]);
            }
        }
    float* o = S2 + 2 * ((size_t)((b * 128 + r2) * 128 + q2) * 64 + c8 * 8);
    #pragma unroll
    for (int k = 0; k < 4; ++k)
        *(float4*)(o + 4 * k) = make_float4(dn[2*k], kp[2*k], dn[2*k+1], kp[2*k+1]);
}

// ---------------- ratio: 4x4 cells -> kp/dn per patch ----------------
__global__ __launch_bounds__(256, 4)
void k_ratio(const float* __restrict__ S2, float* __restrict__ RATIO)
{
    int t = blockIdx.x * 256 + threadIdx.x;
    int cf = t & 63;
    int j  = (t >> 6) & 63;
    int i  = (t >> 12) & 63;
    int b  = t >> 18;
    float dn = 0.f, kp = 0.f;
    #pragma unroll
    for (int u = 0; u < 4; ++u) {
        int r2 = 2 * i - 1 + u;
        if ((unsigned)r2 >= 128u) continue;
        #pragma unroll
        for (int v = 0; v < 4; ++v) {
            int q2 = 2 * j - 1 + v;
            if ((unsigned)q2 >= 128u) continue;
            float2 s = *(const float2*)(S2 + 2 * (((b * 128 + r2) * 128 + q2) * 64 + cf));
            dn += s.x;
            kp += s.y;
        }
    }
    RATIO[t] = (dn == 0.f) ? 0.f : kp * __builtin_amdgcn_rcpf(dn);
}

// ---------------- out: gather 4 phase ratios, dot with bf ----------------
__global__ __launch_bounds__(256, 4)
void k_out(const _Float16* __restrict__ BF, const float* __restrict__ RATIO,
           float* __restrict__ out)
{
    int tid = blockIdx.x * 256 + threadIdx.x;
    int c = tid & 15;
    int q = (tid >> 4) & 255;
    int r = (tid >> 12) & 255;
    int b = tid >> 20;
    int i0 = (r <= 253) ? (((r + 2) >> 3) << 1)        : -1;
    int i1 = (r >= 2)   ? ((((r - 2) >> 3) << 1) | 1)  : -1;
    int j0 = (q <= 253) ? (((q + 2) >> 3) << 1)        : -1;
    int j1 = (q >= 2)   ? ((((q - 2) >> 3) << 1) | 1)  : -1;
    float Sx = 0.f, Sy = 0.f, Sz = 0.f, Sw = 0.f;
    const float* Rb = &RATIO[(size_t)b * 64 * 64 * 64 + 4 * c];
    #pragma unroll
    for (int pi = 0; pi < 2; ++pi) {
        int ii = pi ? i1 : i0;
        if (ii < 0) continue;
        #pragma unroll
        for (int pj = 0; pj < 2; ++pj) {
            int jj = pj ? j1 : j0;
            if (jj < 0) continue;
            float4 r4 = *(const float4*)&Rb[(ii * 64 + jj) * 64];
            Sx += r4.x; Sy += r4.y; Sz += r4.z; Sw += r4.w;
        }
    }
    half4 bf4 = *(const half4*)(BF + (size_t)tid * 4);
    out[tid] = 0.25f * ((float)bf4[0] * Sx + (float)bf4[1] * Sy +
                        (float)bf4[2] * Sz + (float)bf4[3] * Sw);
}

extern "C" void kernel_launch(void* const* d_in, const int* in_sizes, int n_in,
                              void* d_out, int out_size, void* d_ws, size_t ws_size,
                              hipStream_t stream) {
    const float* mr  = (const float*)d_in[0];
    const float* pet = (const float*)d_in[1];
    const float* W1  = (const float*)d_in[2];
    const float* b1  = (const float*)d_in[3];
    const float* g1  = (const float*)d_in[4];
    const float* be1 = (const float*)d_in[5];
    const float* mu1 = (const float*)d_in[6];
    const float* v1  = (const float*)d_in[7];
    const float* W2  = (const float*)d_in[8];
    const float* b2  = (const float*)d_in[9];
    const float* g2  = (const float*)d_in[10];
    const float* be2 = (const float*)d_in[11];
    const float* mu2 = (const float*)d_in[12];
    const float* v2  = (const float*)d_in[13];

    // workspace layout (bytes):
    //   [0,        25165824)  A   f16 (3*256*256*64)
    //   [25165824, 50331648)  BF  f16 (3*256*256*64)
    //   [50331648, 75497472)  S2  fp32 (3*128*128*64*2)
    //   [75497472, 78643200)  RATIO fp32 (3*64*64*64)
    //   [78643200, 78663680)  W1F f16 (5*4*64*8)
    //   [78663680, 78737408)  W2F f16 (18*4*64*8)
    //   [78737408, 78738432)  ST  fp32 (256)
    char* ws = (char*)d_ws;
    _Float16* A     = (_Float16*)(ws);
    _Float16* BF    = (_Float16*)(ws + 25165824);
    float*    S2    = (float*)(ws + 50331648);
    float*    RATIO = (float*)(ws + 75497472);
    _Float16* W1F   = (_Float16*)(ws + 78643200);
    _Float16* W2F   = (_Float16*)(ws + 78663680);
    float*    ST    = (float*)(ws + 78737408);
    float*    out   = (float*)d_out;

    dim3 blk(256);
    k_prep<<<185, blk, 0, stream>>>(W1, W2, b1, g1, be1, mu1, v1,
                                    b2, g2, be2, mu2, v2, W1F, W2F, ST);
    k_conv1<<<dim3(256, 3), blk, 0, stream>>>(mr, W1F, ST, A);
    k_conv2<<<dim3(256, 3), blk, 0, stream>>>(A, W2F, ST, BF);
    k_s2<<<1536, blk, 0, stream>>>(BF, pet, S2);
    k_ratio<<<3072, blk, 0, stream>>>(S2, RATIO);
    k_out<<<12288, blk, 0, stream>>>(BF, RATIO, out);
}

// Round 4
// 177.082 us; speedup vs baseline: 2.7596x; 1.0033x over previous
//
#include <hip/hip_runtime.h>

#define EPSB 1e-3f

typedef _Float16 half8 __attribute__((ext_vector_type(8)));
typedef _Float16 half4 __attribute__((ext_vector_type(4)));
typedef float f32x4 __attribute__((ext_vector_type(4)));

// ---------------- prep: weights -> MFMA-fragment order (f16), BN fold ----------------
// WF layout: frag (s, ct) is 1 KB: WF[((s*4+ct)*64 + lane)*8 + k]
// A-operand mapping (16x16x32): m = lane&15 -> co = ct*16 + (lane&15)
//                               k = (lane>>4)*8 + j -> K index
__global__ __launch_bounds__(256, 4)
void k_prep(const float* __restrict__ W1, const float* __restrict__ W2,
            const float* __restrict__ b1, const float* __restrict__ g1,
            const float* __restrict__ be1, const float* __restrict__ mu1,
            const float* __restrict__ v1,
            const float* __restrict__ b2, const float* __restrict__ g2,
            const float* __restrict__ be2, const float* __restrict__ mu2,
            const float* __restrict__ v2,
            _Float16* __restrict__ W1F, _Float16* __restrict__ W2F,
            float* __restrict__ ST)
{
    int t = blockIdx.x * 256 + threadIdx.x;
    if (t < 5 * 4 * 64 * 8) {                 // W1F
        int k = t & 7, lane = (t >> 3) & 63, snt = t >> 9;
        int s = snt >> 2, ct = snt & 3;
        int quad = lane >> 4, n16 = lane & 15;
        int tap = 2 * s + (quad >> 1);
        int ci  = (quad & 1) * 8 + k;
        int co  = ct * 16 + n16;
        float v = (tap < 9) ? W1[(tap * 16 + ci) * 64 + co] : 0.f;
        W1F[t] = (_Float16)v;
        return;
    }
    t -= 5 * 4 * 64 * 8;
    if (t < 18 * 4 * 64 * 8) {                // W2F
        int k = t & 7, lane = (t >> 3) & 63, snt = t >> 9;
        int s = snt >> 2, ct = snt & 3;
        int quad = lane >> 4, n16 = lane & 15;
        int tap = s >> 1;
        int ci  = (s & 1) * 32 + quad * 8 + k;
        int co  = ct * 16 + n16;
        W2F[t] = (_Float16)W2[(tap * 64 + ci) * 64 + co];
        return;
    }
    t -= 18 * 4 * 64 * 8;
    if (t < 256) {
        int c = t & 63, sel = t >> 6;
        if (sel == 0)      ST[c]       = g1[c] * rsqrtf(v1[c] + EPSB);
        else if (sel == 1) ST[64 + c]  = (b1[c] - mu1[c]) * (g1[c] * rsqrtf(v1[c] + EPSB)) + be1[c];
        else if (sel == 2) ST[128 + c] = g2[c] * rsqrtf(v2[c] + EPSB);
        else               ST[192 + c] = (b2[c] - mu2[c]) * (g2[c] * rsqrtf(v2[c] + EPSB)) + be2[c];
    }
}

// ---------------- conv1: 16->64, MFMA (weights=A from global), BN+ReLU, f16 out ----------------
#define CIP1 24   // padded pixel stride in f16 (48 B)
__global__ __launch_bounds__(256, 3)
void k_conv1(const float* __restrict__ mr, const _Float16* __restrict__ W1F,
             const float* __restrict__ ST, _Float16* __restrict__ A)
{
    __shared__ __align__(16) _Float16 sIn[6 * 66 * CIP1];
    const int tid = threadIdx.x;
    const int b  = blockIdx.y;
    const int r0 = (blockIdx.x >> 2) * 4;
    const int q0 = (blockIdx.x & 3) * 64;

    for (int idx = tid; idx < 6 * 66 * 2; idx += 256) {
        int c = idx & 1, pp = idx >> 1;
        int p = pp % 66, dy = pp / 66;
        int rr = r0 + dy - 1, qg = q0 + p - 1;
        half8 h = (half8)(_Float16)0.f;
        if ((unsigned)rr < 256u && (unsigned)qg < 256u) {
            const float* src = mr + ((b * 256 + rr) * 256 + qg) * 16 + c * 8;
            float4 v0 = *(const float4*)src;
            float4 v1 = *(const float4*)(src + 4);
            h = (half8){(_Float16)v0.x, (_Float16)v0.y, (_Float16)v0.z, (_Float16)v0.w,
                        (_Float16)v1.x, (_Float16)v1.y, (_Float16)v1.z, (_Float16)v1.w};
        }
        *(half8*)(&sIn[(dy * 66 + p) * CIP1 + c * 8]) = h;
    }
    __syncthreads();

    const int w = tid >> 6, lane = tid & 63;
    const int n16 = lane & 15, quad = lane >> 4;
    const int ci0 = (quad & 1) * 8;

    f32x4 acc[4][4];   // [qt][ct]
    #pragma unroll
    for (int i = 0; i < 4; ++i)
        #pragma unroll
        for (int j = 0; j < 4; ++j) acc[i][j] = (f32x4){0.f, 0.f, 0.f, 0.f};

    #pragma unroll
    for (int s = 0; s < 5; ++s) {
        int tap  = 2 * s + (quad >> 1);
        int tapc = tap > 8 ? 8 : tap;
        int dy = tapc / 3, dx = tapc % 3;
        half8 wfrag[4], pfrag[4];
        #pragma unroll
        for (int ct = 0; ct < 4; ++ct)
            wfrag[ct] = *(const half8*)(W1F + ((s * 4 + ct) * 64 + lane) * 8);
        #pragma unroll
        for (int qt = 0; qt < 4; ++qt)
            pfrag[qt] = *(const half8*)&sIn[((w + dy) * 66 + qt * 16 + n16 + dx) * CIP1 + ci0];
        #pragma unroll
        for (int qt = 0; qt < 4; ++qt)
            #pragma unroll
            for (int ct = 0; ct < 4; ++ct)
                acc[qt][ct] = __builtin_amdgcn_mfma_f32_16x16x32_f16(wfrag[ct], pfrag[qt], acc[qt][ct], 0, 0, 0);
    }

    const int r = r0 + w;
    #pragma unroll
    for (int ct = 0; ct < 4; ++ct) {
        int co0 = ct * 16 + quad * 4;
        f32x4 sc = *(const f32x4*)&ST[co0];
        f32x4 sh = *(const f32x4*)&ST[64 + co0];
        #pragma unroll
        for (int qt = 0; qt < 4; ++qt) {
            int q = q0 + qt * 16 + n16;
            half4 h;
            #pragma unroll
            for (int j = 0; j < 4; ++j)
                h[j] = (_Float16)fmaxf(acc[qt][ct][j] * sc[j] + sh[j], 0.f);
            *(half4*)(A + (((b * 256 + r) * 256 + q) * 64 + co0)) = h;
        }
    }
}

// ------- conv2: 64->64 MFMA + BN + in-lane softmax(4)+mask + fused 2x2 cell sums (s2) -------
#define CIP2 72   // padded pixel stride in f16 (144 B)
__global__ __launch_bounds__(256, 2)
void k_conv2(const _Float16* __restrict__ A, const _Float16* __restrict__ W2F,
             const float* __restrict__ ST, const float* __restrict__ pet,
             _Float16* __restrict__ BF, float* __restrict__ S2)
{
    __shared__ __align__(16) _Float16 sIn[6 * 66 * CIP2];   // 57,024 B; reused for BF tile
    const int tid = threadIdx.x;
    const int b  = blockIdx.y;
    const int r0 = (blockIdx.x >> 2) * 4;
    const int q0 = (blockIdx.x & 3) * 64;

    for (int idx = tid; idx < 6 * 66 * 8; idx += 256) {
        int c = idx & 7, pp = idx >> 3;
        int p = pp % 66, dy = pp / 66;
        int rr = r0 + dy - 1, qg = q0 + p - 1;
        int4 v = {0, 0, 0, 0};
        if ((unsigned)rr < 256u && (unsigned)qg < 256u)
            v = *(const int4*)(A + (((b * 256 + rr) * 256 + qg) * 64 + c * 8));
        *(int4*)(&sIn[(dy * 66 + p) * CIP2 + c * 8]) = v;
    }
    __syncthreads();

    const int w = tid >> 6, lane = tid & 63;
    const int n16 = lane & 15, quad = lane >> 4;

    f32x4 acc[4][4];   // [qt][ct]
    #pragma unroll
    for (int i = 0; i < 4; ++i)
        #pragma unroll
        for (int j = 0; j < 4; ++j) acc[i][j] = (f32x4){0.f, 0.f, 0.f, 0.f};

    #pragma unroll
    for (int s = 0; s < 18; ++s) {
        const int tap = s >> 1;
        const int dy = tap / 3, dx = tap % 3;
        const int ci0 = (s & 1) * 32 + quad * 8;
        half8 wfrag[4], pfrag[4];
        #pragma unroll
        for (int ct = 0; ct < 4; ++ct)
            wfrag[ct] = *(const half8*)(W2F + ((s * 4 + ct) * 64 + lane) * 8);
        #pragma unroll
        for (int qt = 0; qt < 4; ++qt)
            pfrag[qt] = *(const half8*)&sIn[((w + dy) * 66 + qt * 16 + n16 + dx) * CIP2 + ci0];
        #pragma unroll
        for (int qt = 0; qt < 4; ++qt)
            #pragma unroll
            for (int ct = 0; ct < 4; ++ct)
                acc[qt][ct] = __builtin_amdgcn_mfma_f32_16x16x32_f16(wfrag[ct], pfrag[qt], acc[qt][ct], 0, 0, 0);
    }

    // BN + softmax + mask into registers, store global BF
    const int r = r0 + w;
    half4 hv[4][4];     // [ct][qt]
    #pragma unroll
    for (int ct = 0; ct < 4; ++ct) {
        int co0 = ct * 16 + quad * 4;     // softmax group co0..co0+3, all in-lane
        f32x4 sc = *(const f32x4*)&ST[128 + co0];
        f32x4 sh = *(const f32x4*)&ST[192 + co0];
        #pragma unroll
        for (int qt = 0; qt < 4; ++qt) {
            int q = q0 + qt * 16 + n16;
            float z0 = acc[qt][ct][0] * sc[0] + sh[0];
            float z1 = acc[qt][ct][1] * sc[1] + sh[1];
            float z2 = acc[qt][ct][2] * sc[2] + sh[2];
            float z3 = acc[qt][ct][3] * sc[3] + sh[3];
            float mx = fmaxf(fmaxf(z0, z1), fmaxf(z2, z3));
            float e0 = __expf(z0 - mx), e1 = __expf(z1 - mx);
            float e2 = __expf(z2 - mx), e3 = __expf(z3 - mx);
            float inv = __builtin_amdgcn_rcpf((e0 + e1) + (e2 + e3));
            float p0 = e0 * inv, p1 = e1 * inv, p2 = e2 * inv, p3 = e3 * inv;
            half4 h;
            h[0] = (_Float16)(p0 > 1e-5f ? p0 : 0.f);
            h[1] = (_Float16)(p1 > 1e-5f ? p1 : 0.f);
            h[2] = (_Float16)(p2 > 1e-5f ? p2 : 0.f);
            h[3] = (_Float16)(p3 > 1e-5f ? p3 : 0.f);
            hv[ct][qt] = h;
            *(half4*)(BF + (((b * 256 + r) * 256 + q) * 64 + co0)) = h;
        }
    }

    // ---- fused s2: 2x2 pixel cell sums of (dn, pet*bf) via LDS round-trip ----
    __syncthreads();   // MFMA-phase LDS reads done everywhere
    #pragma unroll
    for (int ct = 0; ct < 4; ++ct) {
        int co0 = ct * 16 + quad * 4;
        #pragma unroll
        for (int qt = 0; qt < 4; ++qt) {
            int ql = qt * 16 + n16;
            *(half4*)(&sIn[(w * 64 + ql) * CIP2 + co0]) = hv[ct][qt];
        }
    }
    __syncthreads();

    // 256 threads: 64 cells (2 rp x 32 qp) x 4 cf-groups of 16
    const int k4 = tid & 3;           // cf in [16*k4, 16*k4+16)
    const int cell = tid >> 2;        // 0..63
    const int rp = cell >> 5, qp = cell & 31;
    float dn[16], kp[16];
    #pragma unroll
    for (int j = 0; j < 16; ++j) { dn[j] = 0.f; kp[j] = 0.f; }
    #pragma unroll
    for (int u = 0; u < 2; ++u)
        #pragma unroll
        for (int v = 0; v < 2; ++v) {
            int rl = 2 * rp + u, ql = 2 * qp + v;
            half8 b0 = *(const half8*)(&sIn[(rl * 64 + ql) * CIP2 + k4 * 16]);
            half8 b1 = *(const half8*)(&sIn[(rl * 64 + ql) * CIP2 + k4 * 16 + 8]);
            float4 p4 = *(const float4*)(pet + ((b * 256 + r0 + rl) * 256 + q0 + ql) * 16 + 4 * k4);
            #pragma unroll
            for (int j = 0; j < 8; ++j) {
                float bv = (float)b0[j];
                dn[j] += bv;
                kp[j] = fmaf((j < 4) ? p4.x : p4.y, bv, kp[j]);
            }
            #pragma unroll
            for (int j = 0; j < 8; ++j) {
                float bv = (float)b1[j];
                dn[8 + j] += bv;
                kp[8 + j] = fmaf((j < 4) ? p4.z : p4.w, bv, kp[8 + j]);
            }
        }
    float* o = S2 + 2 * ((size_t)(((b * 128 + (r0 >> 1) + rp) * 128 + (q0 >> 1) + qp) * 64) + 16 * k4);
    #pragma unroll
    for (int m = 0; m < 8; ++m)
        *(float4*)(o + 4 * m) = make_float4(dn[2*m], kp[2*m], dn[2*m+1], kp[2*m+1]);
}

// ---------------- ratio: 4x4 cells -> 0.25 * kp/dn per patch ----------------
__global__ __launch_bounds__(256, 4)
void k_ratio(const float* __restrict__ S2, float* __restrict__ RATIO)
{
    int t = blockIdx.x * 256 + threadIdx.x;
    int cf = t & 63;
    int j  = (t >> 6) & 63;
    int i  = (t >> 12) & 63;
    int b  = t >> 18;
    float dn = 0.f, kp = 0.f;
    #pragma unroll
    for (int u = 0; u < 4; ++u) {
        int r2 = 2 * i - 1 + u;
        if ((unsigned)r2 >= 128u) continue;
        #pragma unroll
        for (int v = 0; v < 4; ++v) {
            int q2 = 2 * j - 1 + v;
            if ((unsigned)q2 >= 128u) continue;
            float2 s = *(const float2*)(S2 + 2 * (((b * 128 + r2) * 128 + q2) * 64 + cf));
            dn += s.x;
            kp += s.y;
        }
    }
    RATIO[t] = (dn == 0.f) ? 0.f : 0.25f * kp * __builtin_amdgcn_rcpf(dn);
}

// ---------------- out: stage 2 RATIO i-rows in LDS, dot with bf ----------------
__global__ __launch_bounds__(256, 4)
void k_out(const _Float16* __restrict__ BF, const float* __restrict__ RATIO,
           float* __restrict__ out)
{
    __shared__ __align__(16) float sR[2 * 64 * 68];   // [ph][j][cf], row padded to 68
    const int tid = threadIdx.x;
    const int r = blockIdx.x & 255;
    const int b = blockIdx.x >> 8;

    const int i0 = (r <= 253) ? 2 * ((r + 2) >> 3)       : -1;
    const int i1 = (r >= 2)   ? 2 * ((r - 2) >> 3) + 1   : -1;

    for (int idx = tid; idx < 2048; idx += 256) {      // 2048 float4s
        int ph = idx >> 10, rest = idx & 1023;
        int j = rest >> 4, c4 = rest & 15;
        int ii = ph ? i1 : i0;
        float4 v = make_float4(0.f, 0.f, 0.f, 0.f);
        if (ii >= 0)
            v = *(const float4*)&RATIO[(((b * 64 + ii) * 64 + j) << 6) + 4 * c4];
        *(float4*)&sR[(ph * 64 + j) * 68 + 4 * c4] = v;
    }
    __syncthreads();

    const int q = tid;
    const int j0 = (q <= 253) ? 2 * ((q + 2) >> 3)     : -1;
    const int j1 = (q >= 2)   ? 2 * ((q - 2) >> 3) + 1 : -1;

    const half8* bfp = (const half8*)(BF + ((size_t)(b * 256 + r) * 256 + q) * 64);
    float o[16];
    #pragma unroll
    for (int c = 0; c < 16; ++c) o[c] = 0.f;

    #pragma unroll
    for (int c2 = 0; c2 < 8; ++c2) {
        half8 bf8 = bfp[c2];
        float s0 = 0.f, s1 = 0.f;
        #pragma unroll
        for (int pi = 0; pi < 2; ++pi) {
            #pragma unroll
            for (int pj = 0; pj < 2; ++pj) {
                int jj = pj ? j1 : j0;
                if (jj < 0) continue;
                const float* rp_ = &sR[(pi * 64 + jj) * 68 + 8 * c2];
                s0 += (float)bf8[0] * rp_[0] + (float)bf8[1] * rp_[1]
                    + (float)bf8[2] * rp_[2] + (float)bf8[3] * rp_[3];
                s1 += (float)bf8[4] * rp_[4] + (float)bf8[5] * rp_[5]
                    + (float)bf8[6] * rp_[6] + (float)bf8[7] * rp_[7];
            }
        }
        o[2 * c2]     = s0;
        o[2 * c2 + 1] = s1;
    }
    float* op = out + ((size_t)(b * 256 + r) * 256 + q) * 16;
    #pragma unroll
    for (int m = 0; m < 4; ++m)
        *(float4*)(op + 4 * m) = make_float4(o[4*m], o[4*m+1], o[4*m+2], o[4*m+3]);
}

extern "C" void kernel_launch(void* const* d_in, const int* in_sizes, int n_in,
                              void* d_out, int out_size, void* d_ws, size_t ws_size,
                              hipStream_t stream) {
    const float* mr  = (const float*)d_in[0];
    const float* pet = (const float*)d_in[1];
    const float* W1  = (const float*)d_in[2];
    const float* b1  = (const float*)d_in[3];
    const float* g1  = (const float*)d_in[4];
    const float* be1 = (const float*)d_in[5];
    const float* mu1 = (const float*)d_in[6];
    const float* v1  = (const float*)d_in[7];
    const float* W2  = (const float*)d_in[8];
    const float* b2  = (const float*)d_in[9];
    const float* g2  = (const float*)d_in[10];
    const float* be2 = (const float*)d_in[11];
    const float* mu2 = (const float*)d_in[12];
    const float* v2  = (const float*)d_in[13];

    // workspace layout (bytes):
    //   [0,        25165824)  A   f16 (3*256*256*64)
    //   [25165824, 50331648)  BF  f16 (3*256*256*64)
    //   [50331648, 75497472)  S2  fp32 (3*128*128*64*2)
    //   [75497472, 78643200)  RATIO fp32 (3*64*64*64)
    //   [78643200, 78663680)  W1F f16
    //   [78663680, 78737408)  W2F f16
    //   [78737408, 78738432)  ST  fp32
    char* ws = (char*)d_ws;
    _Float16* A     = (_Float16*)(ws);
    _Float16* BF    = (_Float16*)(ws + 25165824);
    float*    S2    = (float*)(ws + 50331648);
    float*    RATIO = (float*)(ws + 75497472);
    _Float16* W1F   = (_Float16*)(ws + 78643200);
    _Float16* W2F   = (_Float16*)(ws + 78663680);
    float*    ST    = (float*)(ws + 78737408);
    float*    out   = (float*)d_out;

    dim3 blk(256);
    k_prep<<<185, blk, 0, stream>>>(W1, W2, b1, g1, be1, mu1, v1,
                                    b2, g2, be2, mu2, v2, W1F, W2F, ST);
    k_conv1<<<dim3(256, 3), blk, 0, stream>>>(mr, W1F, ST, A);
    k_conv2<<<dim3(256, 3), blk, 0, stream>>>(A, W2F, ST, pet, BF, S2);
    k_ratio<<<3072, blk, 0, stream>>>(S2, RATIO);
    k_out<<<768, blk, 0, stream>>>(BF, RATIO, out);
}

// Round 5
// 171.725 us; speedup vs baseline: 2.8456x; 1.0312x over previous
//
#include <hip/hip_runtime.h>

#define EPSB 1e-3f

typedef _Float16 half8 __attribute__((ext_vector_type(8)));
typedef _Float16 half4 __attribute__((ext_vector_type(4)));
typedef float f32x4 __attribute__((ext_vector_type(4)));

// ---------------- prep: weights -> MFMA-fragment order (f16), BN fold ----------------
// WF layout: frag (s, ct) is 1 KB: WF[((s*4+ct)*64 + lane)*8 + k]
// A-operand mapping (16x16x32): m = lane&15 -> co = ct*16 + (lane&15)
//                               k = (lane>>4)*8 + j -> K index
__global__ __launch_bounds__(256, 4)
void k_prep(const float* __restrict__ W1, const float* __restrict__ W2,
            const float* __restrict__ b1, const float* __restrict__ g1,
            const float* __restrict__ be1, const float* __restrict__ mu1,
            const float* __restrict__ v1,
            const float* __restrict__ b2, const float* __restrict__ g2,
            const float* __restrict__ be2, const float* __restrict__ mu2,
            const float* __restrict__ v2,
            _Float16* __restrict__ W1F, _Float16* __restrict__ W2F,
            float* __restrict__ ST)
{
    int t = blockIdx.x * 256 + threadIdx.x;
    if (t < 5 * 4 * 64 * 8) {                 // W1F
        int k = t & 7, lane = (t >> 3) & 63, snt = t >> 9;
        int s = snt >> 2, ct = snt & 3;
        int quad = lane >> 4, n16 = lane & 15;
        int tap = 2 * s + (quad >> 1);
        int ci  = (quad & 1) * 8 + k;
        int co  = ct * 16 + n16;
        float v = (tap < 9) ? W1[(tap * 16 + ci) * 64 + co] : 0.f;
        W1F[t] = (_Float16)v;
        return;
    }
    t -= 5 * 4 * 64 * 8;
    if (t < 18 * 4 * 64 * 8) {                // W2F
        int k = t & 7, lane = (t >> 3) & 63, snt = t >> 9;
        int s = snt >> 2, ct = snt & 3;
        int quad = lane >> 4, n16 = lane & 15;
        int tap = s >> 1;
        int ci  = (s & 1) * 32 + quad * 8 + k;
        int co  = ct * 16 + n16;
        W2F[t] = (_Float16)W2[(tap * 64 + ci) * 64 + co];
        return;
    }
    t -= 18 * 4 * 64 * 8;
    if (t < 256) {
        int c = t & 63, sel = t >> 6;
        if (sel == 0)      ST[c]       = g1[c] * rsqrtf(v1[c] + EPSB);
        else if (sel == 1) ST[64 + c]  = (b1[c] - mu1[c]) * (g1[c] * rsqrtf(v1[c] + EPSB)) + be1[c];
        else if (sel == 2) ST[128 + c] = g2[c] * rsqrtf(v2[c] + EPSB);
        else               ST[192 + c] = (b2[c] - mu2[c]) * (g2[c] * rsqrtf(v2[c] + EPSB)) + be2[c];
    }
}

// ---------------- conv1: 16->64, MFMA, BN+ReLU, coalesced f16 out ----------------
// tile 2r x 64q; wave w: row = w>>1, q-half = (w&1)*32; acc[2][4] (32q x 64co)
#define CIP1 24   // padded pixel stride in f16 (48 B) for input stage
__global__ __launch_bounds__(256, 4)
void k_conv1(const float* __restrict__ mr, const _Float16* __restrict__ W1F,
             const float* __restrict__ ST, _Float16* __restrict__ A)
{
    __shared__ __align__(16) _Float16 sM[2 * 64 * 72];   // 18,432 B (input stage uses 4*66*24=6336)
    const int tid = threadIdx.x;
    const int b  = blockIdx.y;
    const int r0 = (blockIdx.x >> 2) * 2;
    const int q0 = (blockIdx.x & 3) * 64;

    for (int idx = tid; idx < 4 * 66 * 2; idx += 256) {
        int c = idx & 1, pp = idx >> 1;
        int p = pp % 66, dy = pp / 66;
        int rr = r0 + dy - 1, qg = q0 + p - 1;
        half8 h = (half8)(_Float16)0.f;
        if ((unsigned)rr < 256u && (unsigned)qg < 256u) {
            const float* src = mr + ((b * 256 + rr) * 256 + qg) * 16 + c * 8;
            float4 v0 = *(const float4*)src;
            float4 v1 = *(const float4*)(src + 4);
            h = (half8){(_Float16)v0.x, (_Float16)v0.y, (_Float16)v0.z, (_Float16)v0.w,
                        (_Float16)v1.x, (_Float16)v1.y, (_Float16)v1.z, (_Float16)v1.w};
        }
        *(half8*)(&sM[(dy * 66 + p) * CIP1 + c * 8]) = h;
    }
    __syncthreads();

    const int w = tid >> 6, lane = tid & 63;
    const int n16 = lane & 15, quad = lane >> 4;
    const int rl = w >> 1, qh = (w & 1) * 32;
    const int ci0 = (quad & 1) * 8;

    f32x4 acc[2][4];   // [qt][ct]
    #pragma unroll
    for (int i = 0; i < 2; ++i)
        #pragma unroll
        for (int j = 0; j < 4; ++j) acc[i][j] = (f32x4){0.f, 0.f, 0.f, 0.f};

    #pragma unroll
    for (int s = 0; s < 5; ++s) {
        int tap  = 2 * s + (quad >> 1);
        int tapc = tap > 8 ? 8 : tap;
        int dy = tapc / 3, dx = tapc % 3;
        half8 wfrag[4], pfrag[2];
        #pragma unroll
        for (int ct = 0; ct < 4; ++ct)
            wfrag[ct] = *(const half8*)(W1F + ((s * 4 + ct) * 64 + lane) * 8);
        #pragma unroll
        for (int qt = 0; qt < 2; ++qt)
            pfrag[qt] = *(const half8*)&sM[((rl + dy) * 66 + qh + qt * 16 + n16 + dx) * CIP1 + ci0];
        #pragma unroll
        for (int qt = 0; qt < 2; ++qt)
            #pragma unroll
            for (int ct = 0; ct < 4; ++ct)
                acc[qt][ct] = __builtin_amdgcn_mfma_f32_16x16x32_f16(wfrag[ct], pfrag[qt], acc[qt][ct], 0, 0, 0);
    }

    // BN + ReLU -> registers
    half4 hv[4][2];
    #pragma unroll
    for (int ct = 0; ct < 4; ++ct) {
        int co0 = ct * 16 + quad * 4;
        f32x4 sc = *(const f32x4*)&ST[co0];
        f32x4 sh = *(const f32x4*)&ST[64 + co0];
        #pragma unroll
        for (int qt = 0; qt < 2; ++qt) {
            half4 h;
            #pragma unroll
            for (int j = 0; j < 4; ++j)
                h[j] = (_Float16)fmaxf(acc[qt][ct][j] * sc[j] + sh[j], 0.f);
            hv[ct][qt] = h;
        }
    }
    __syncthreads();
    #pragma unroll
    for (int ct = 0; ct < 4; ++ct) {
        int co0 = ct * 16 + quad * 4;
        #pragma unroll
        for (int qt = 0; qt < 2; ++qt) {
            int ql = qh + qt * 16 + n16;
            *(half4*)(&sM[(rl * 64 + ql) * 72 + co0]) = hv[ct][qt];
        }
    }
    __syncthreads();

    // coalesced A store: 2 rows x 64 q x 64 ch f16 = 1024 int4
    for (int idx = tid; idx < 1024; idx += 256) {
        int rl2 = idx >> 9, rest = idx & 511;
        int ql = rest >> 3, seg = rest & 7;
        int4 v = *(const int4*)&sM[(rl2 * 64 + ql) * 72 + seg * 8];
        *(int4*)(A + (((b * 256 + r0 + rl2) * 256 + q0 + ql) * 64 + seg * 8)) = v;
    }
}

// ------- conv2: 64->64 MFMA + BN + in-lane softmax(4)+mask + fused s2, coalesced stores -------
#define CIP2 72   // padded pixel stride in f16 (144 B)
__global__ __launch_bounds__(256, 4)
void k_conv2(const _Float16* __restrict__ A, const _Float16* __restrict__ W2F,
             const float* __restrict__ ST, const float* __restrict__ pet,
             _Float16* __restrict__ BF, float* __restrict__ S2)
{
    __shared__ __align__(16) _Float16 sM[4 * 66 * CIP2];   // 38,016 B; reused for BF tile
    const int tid = threadIdx.x;
    const int b  = blockIdx.y;
    const int r0 = (blockIdx.x >> 2) * 2;
    const int q0 = (blockIdx.x & 3) * 64;

    for (int idx = tid; idx < 4 * 66 * 8; idx += 256) {
        int c = idx & 7, pp = idx >> 3;
        int p = pp % 66, dy = pp / 66;
        int rr = r0 + dy - 1, qg = q0 + p - 1;
        int4 v = {0, 0, 0, 0};
        if ((unsigned)rr < 256u && (unsigned)qg < 256u)
            v = *(const int4*)(A + (((b * 256 + rr) * 256 + qg) * 64 + c * 8));
        *(int4*)(&sM[(dy * 66 + p) * CIP2 + c * 8]) = v;
    }
    __syncthreads();

    const int w = tid >> 6, lane = tid & 63;
    const int n16 = lane & 15, quad = lane >> 4;
    const int rl = w >> 1, qh = (w & 1) * 32;

    f32x4 acc[2][4];   // [qt][ct]
    #pragma unroll
    for (int i = 0; i < 2; ++i)
        #pragma unroll
        for (int j = 0; j < 4; ++j) acc[i][j] = (f32x4){0.f, 0.f, 0.f, 0.f};

    #pragma unroll
    for (int s = 0; s < 18; ++s) {
        const int tap = s >> 1;
        const int dy = tap / 3, dx = tap % 3;
        const int ci0 = (s & 1) * 32 + quad * 8;
        half8 wfrag[4], pfrag[2];
        #pragma unroll
        for (int ct = 0; ct < 4; ++ct)
            wfrag[ct] = *(const half8*)(W2F + ((s * 4 + ct) * 64 + lane) * 8);
        #pragma unroll
        for (int qt = 0; qt < 2; ++qt)
            pfrag[qt] = *(const half8*)&sM[((rl + dy) * 66 + qh + qt * 16 + n16 + dx) * CIP2 + ci0];
        #pragma unroll
        for (int qt = 0; qt < 2; ++qt)
            #pragma unroll
            for (int ct = 0; ct < 4; ++ct)
                acc[qt][ct] = __builtin_amdgcn_mfma_f32_16x16x32_f16(wfrag[ct], pfrag[qt], acc[qt][ct], 0, 0, 0);
    }

    // BN + softmax(4 in-lane) + mask -> registers
    half4 hv[4][2];
    #pragma unroll
    for (int ct = 0; ct < 4; ++ct) {
        int co0 = ct * 16 + quad * 4;
        f32x4 sc = *(const f32x4*)&ST[128 + co0];
        f32x4 sh = *(const f32x4*)&ST[192 + co0];
        #pragma unroll
        for (int qt = 0; qt < 2; ++qt) {
            float z0 = acc[qt][ct][0] * sc[0] + sh[0];
            float z1 = acc[qt][ct][1] * sc[1] + sh[1];
            float z2 = acc[qt][ct][2] * sc[2] + sh[2];
            float z3 = acc[qt][ct][3] * sc[3] + sh[3];
            float mx = fmaxf(fmaxf(z0, z1), fmaxf(z2, z3));
            float e0 = __expf(z0 - mx), e1 = __expf(z1 - mx);
            float e2 = __expf(z2 - mx), e3 = __expf(z3 - mx);
            float inv = __builtin_amdgcn_rcpf((e0 + e1) + (e2 + e3));
            float p0 = e0 * inv, p1 = e1 * inv, p2 = e2 * inv, p3 = e3 * inv;
            half4 h;
            h[0] = (_Float16)(p0 > 1e-5f ? p0 : 0.f);
            h[1] = (_Float16)(p1 > 1e-5f ? p1 : 0.f);
            h[2] = (_Float16)(p2 > 1e-5f ? p2 : 0.f);
            h[3] = (_Float16)(p3 > 1e-5f ? p3 : 0.f);
            hv[ct][qt] = h;
        }
    }
    __syncthreads();   // all pfrag reads done -> safe to overwrite sM
    #pragma unroll
    for (int ct = 0; ct < 4; ++ct) {
        int co0 = ct * 16 + quad * 4;
        #pragma unroll
        for (int qt = 0; qt < 2; ++qt) {
            int ql = qh + qt * 16 + n16;
            *(half4*)(&sM[(rl * 64 + ql) * CIP2 + co0]) = hv[ct][qt];
        }
    }
    __syncthreads();

    // coalesced BF store: 2 rows x 64 q x 64 ch f16 = 1024 int4
    for (int idx = tid; idx < 1024; idx += 256) {
        int rl2 = idx >> 9, rest = idx & 511;
        int ql = rest >> 3, seg = rest & 7;
        int4 v = *(const int4*)&sM[(rl2 * 64 + ql) * CIP2 + seg * 8];
        *(int4*)(BF + (((b * 256 + r0 + rl2) * 256 + q0 + ql) * 64 + seg * 8)) = v;
    }

    // fused s2: 1 cell-row x 32 cells x 8 ch-groups; coalesced 64 B stores
    const int qp = tid >> 3, chg = tid & 7;
    float dn[8], kp[8];
    #pragma unroll
    for (int j = 0; j < 8; ++j) { dn[j] = 0.f; kp[j] = 0.f; }
    #pragma unroll
    for (int u = 0; u < 2; ++u)
        #pragma unroll
        for (int v = 0; v < 2; ++v) {
            int ql = 2 * qp + v;
            half8 bf = *(const half8*)(&sM[(u * 64 + ql) * CIP2 + chg * 8]);
            float2 p2 = *(const float2*)(pet + ((b * 256 + r0 + u) * 256 + q0 + ql) * 16 + chg * 2);
            #pragma unroll
            for (int j = 0; j < 8; ++j) {
                float bv = (float)bf[j];
                dn[j] += bv;
                kp[j] = fmaf((j < 4) ? p2.x : p2.y, bv, kp[j]);
            }
        }
    float* o = S2 + 2 * ((size_t)(((b * 128 + (r0 >> 1)) * 128 + (q0 >> 1) + qp) * 64) + chg * 8);
    #pragma unroll
    for (int m = 0; m < 4; ++m)
        *(float4*)(o + 4 * m) = make_float4(dn[2*m], kp[2*m], dn[2*m+1], kp[2*m+1]);
}

// ---------------- ratio: 4x4 cells -> 0.25 * kp/dn per patch ----------------
__global__ __launch_bounds__(256, 4)
void k_ratio(const float* __restrict__ S2, float* __restrict__ RATIO)
{
    int t = blockIdx.x * 256 + threadIdx.x;
    int cf = t & 63;
    int j  = (t >> 6) & 63;
    int i  = (t >> 12) & 63;
    int b  = t >> 18;
    float dn = 0.f, kp = 0.f;
    #pragma unroll
    for (int u = 0; u < 4; ++u) {
        int r2 = 2 * i - 1 + u;
        if ((unsigned)r2 >= 128u) continue;
        #pragma unroll
        for (int v = 0; v < 4; ++v) {
            int q2 = 2 * j - 1 + v;
            if ((unsigned)q2 >= 128u) continue;
            float2 s = *(const float2*)(S2 + 2 * (((b * 128 + r2) * 128 + q2) * 64 + cf));
            dn += s.x;
            kp += s.y;
        }
    }
    RATIO[t] = (dn == 0.f) ? 0.f : 0.25f * kp * __builtin_amdgcn_rcpf(dn);
}

// ---------------- out: stage 2 RATIO i-rows in LDS, dot with bf ----------------
__global__ __launch_bounds__(256, 4)
void k_out(const _Float16* __restrict__ BF, const float* __restrict__ RATIO,
           float* __restrict__ out)
{
    __shared__ __align__(16) float sR[2 * 64 * 68];   // [ph][j][cf], row padded to 68
    const int tid = threadIdx.x;
    const int r = blockIdx.x & 255;
    const int b = blockIdx.x >> 8;

    const int i0 = (r <= 253) ? 2 * ((r + 2) >> 3)       : -1;
    const int i1 = (r >= 2)   ? 2 * ((r - 2) >> 3) + 1   : -1;

    for (int idx = tid; idx < 2048; idx += 256) {      // 2048 float4s
        int ph = idx >> 10, rest = idx & 1023;
        int j = rest >> 4, c4 = rest & 15;
        int ii = ph ? i1 : i0;
        float4 v = make_float4(0.f, 0.f, 0.f, 0.f);
        if (ii >= 0)
            v = *(const float4*)&RATIO[(((b * 64 + ii) * 64 + j) << 6) + 4 * c4];
        *(float4*)&sR[(ph * 64 + j) * 68 + 4 * c4] = v;
    }
    __syncthreads();

    const int q = tid;
    const int j0 = (q <= 253) ? 2 * ((q + 2) >> 3)     : -1;
    const int j1 = (q >= 2)   ? 2 * ((q - 2) >> 3) + 1 : -1;

    const half8* bfp = (const half8*)(BF + ((size_t)(b * 256 + r) * 256 + q) * 64);
    float o[16];
    #pragma unroll
    for (int c = 0; c < 16; ++c) o[c] = 0.f;

    #pragma unroll
    for (int c2 = 0; c2 < 8; ++c2) {
        half8 bf8 = bfp[c2];
        float s0 = 0.f, s1 = 0.f;
        #pragma unroll
        for (int pi = 0; pi < 2; ++pi) {
            #pragma unroll
            for (int pj = 0; pj < 2; ++pj) {
                int jj = pj ? j1 : j0;
                if (jj < 0) continue;
                const float* rp_ = &sR[(pi * 64 + jj) * 68 + 8 * c2];
                s0 += (float)bf8[0] * rp_[0] + (float)bf8[1] * rp_[1]
                    + (float)bf8[2] * rp_[2] + (float)bf8[3] * rp_[3];
                s1 += (float)bf8[4] * rp_[4] + (float)bf8[5] * rp_[5]
                    + (float)bf8[6] * rp_[6] + (float)bf8[7] * rp_[7];
            }
        }
        o[2 * c2]     = s0;
        o[2 * c2 + 1] = s1;
    }
    float* op = out + ((size_t)(b * 256 + r) * 256 + q) * 16;
    #pragma unroll
    for (int m = 0; m < 4; ++m)
        *(float4*)(op + 4 * m) = make_float4(o[4*m], o[4*m+1], o[4*m+2], o[4*m+3]);
}

extern "C" void kernel_launch(void* const* d_in, const int* in_sizes, int n_in,
                              void* d_out, int out_size, void* d_ws, size_t ws_size,
                              hipStream_t stream) {
    const float* mr  = (const float*)d_in[0];
    const float* pet = (const float*)d_in[1];
    const float* W1  = (const float*)d_in[2];
    const float* b1  = (const float*)d_in[3];
    const float* g1  = (const float*)d_in[4];
    const float* be1 = (const float*)d_in[5];
    const float* mu1 = (const float*)d_in[6];
    const float* v1  = (const float*)d_in[7];
    const float* W2  = (const float*)d_in[8];
    const float* b2  = (const float*)d_in[9];
    const float* g2  = (const float*)d_in[10];
    const float* be2 = (const float*)d_in[11];
    const float* mu2 = (const float*)d_in[12];
    const float* v2  = (const float*)d_in[13];

    // workspace layout (bytes):
    //   [0,        25165824)  A   f16 (3*256*256*64)
    //   [25165824, 50331648)  BF  f16 (3*256*256*64)
    //   [50331648, 75497472)  S2  fp32 (3*128*128*64*2)
    //   [75497472, 78643200)  RATIO fp32 (3*64*64*64)
    //   [78643200, 78663680)  W1F f16
    //   [78663680, 78737408)  W2F f16
    //   [78737408, 78738432)  ST  fp32
    char* ws = (char*)d_ws;
    _Float16* A     = (_Float16*)(ws);
    _Float16* BF    = (_Float16*)(ws + 25165824);
    float*    S2    = (float*)(ws + 50331648);
    float*    RATIO = (float*)(ws + 75497472);
    _Float16* W1F   = (_Float16*)(ws + 78643200);
    _Float16* W2F   = (_Float16*)(ws + 78663680);
    float*    ST    = (float*)(ws + 78737408);
    float*    out   = (float*)d_out;

    dim3 blk(256);
    k_prep<<<185, blk, 0, stream>>>(W1, W2, b1, g1, be1, mu1, v1,
                                    b2, g2, be2, mu2, v2, W1F, W2F, ST);
    k_conv1<<<dim3(512, 3), blk, 0, stream>>>(mr, W1F, ST, A);
    k_conv2<<<dim3(512, 3), blk, 0, stream>>>(A, W2F, ST, pet, BF, S2);
    k_ratio<<<3072, blk, 0, stream>>>(S2, RATIO);
    k_out<<<768, blk, 0, stream>>>(BF, RATIO, out);
}